// Round 1
// baseline (114.388 us; speedup 1.0000x reference)
//
#include <hip/hip_runtime.h>

// Problem constants
#define B_SZ  16384
#define F_SZ  20
#define V_SZ  100000
#define E_SZ  32
#define DBOT  640     // F*E
#define D1    512
#define D2    256
#define T1D   128
#define T2D   64
#define NDOM  4

typedef __bf16 bf16x8 __attribute__((ext_vector_type(8)));
typedef float  f32x4  __attribute__((ext_vector_type(4)));

#define GAS __attribute__((address_space(1)))
#define LAS __attribute__((address_space(3)))

__device__ __forceinline__ void gl_lds16(const void* g, void* l) {
  __builtin_amdgcn_global_load_lds((const GAS void*)g, (LAS void*)l, 16, 0, 0);
}

// ---------------------------------------------------------------------------
// Transpose + fp32->bf16 convert:  W (K x N, row-major)  ->  WT (N x K) bf16
// blockIdx.y = batch (domain) index; each batch is K*N elements.
// ---------------------------------------------------------------------------
__global__ __launch_bounds__(256) void k_transpose(const float* __restrict__ W,
                                                   __bf16* __restrict__ WT,
                                                   int K, int N) {
  long base = (long)blockIdx.y * K * N;
  const float* w = W + base;
  __bf16* wt = WT + base;
  int total = K * N;
  for (int idx = blockIdx.x * 256 + threadIdx.x; idx < total;
       idx += gridDim.x * 256) {
    int n = idx / K;
    int k = idx - n * K;
    wt[idx] = (__bf16)w[(long)k * N + n];
  }
}

// ---------------------------------------------------------------------------
// Embedding gather + convert: h[b][f*32+e] = bf16(emb[f][ids[b][f]][e])
// One thread handles 8 consecutive elements (32B in, 16B out).
// ---------------------------------------------------------------------------
__global__ __launch_bounds__(256) void k_gather(const int* __restrict__ fids,
                                                const float* __restrict__ emb,
                                                __bf16* __restrict__ h) {
  int t = blockIdx.x * 256 + threadIdx.x;   // 0 .. B*F*4
  int chunk = t & 3;
  int bf = t >> 2;
  int b = bf / F_SZ;
  int f = bf - b * F_SZ;
  int id = fids[bf];
  const float* src = emb + ((long)f * V_SZ + id) * E_SZ + chunk * 8;
  float4 v0 = *(const float4*)src;
  float4 v1 = *(const float4*)(src + 4);
  bf16x8 o;
  o[0] = (__bf16)v0.x; o[1] = (__bf16)v0.y; o[2] = (__bf16)v0.z; o[3] = (__bf16)v0.w;
  o[4] = (__bf16)v1.x; o[5] = (__bf16)v1.y; o[6] = (__bf16)v1.z; o[7] = (__bf16)v1.w;
  *(bf16x8*)(h + (long)b * DBOT + f * E_SZ + chunk * 8) = o;
}

// ---------------------------------------------------------------------------
// bf16 MFMA GEMM:  C[M][N] = relu(A[M][K] @ B[K][N] + bias),  B given as BT[N][K]
// 128x128 tile, BK=64, 256 threads = 4 waves in 2x2.  m97-style structure:
// global_load_lds(16B) staging, 2 barriers per K-step.
// ---------------------------------------------------------------------------
__global__ __launch_bounds__(256) void k_gemm(const __bf16* __restrict__ A,
                                              const __bf16* __restrict__ BT,
                                              const float* __restrict__ bias,
                                              __bf16* __restrict__ C,
                                              int M, int N, int K, int ntn) {
  __shared__ __bf16 sA[128 * 64];
  __shared__ __bf16 sB[128 * 64];
  int bid = blockIdx.x;
  int mt = bid / ntn, nt = bid - mt * ntn;
  long m0 = (long)mt * 128;
  int n0 = nt * 128;
  int tid  = threadIdx.x;
  int lane = tid & 63;
  int w    = tid >> 6;
  int wr = w >> 1, wc = w & 1;
  int lrow = lane & 15;
  int lko  = (lane >> 4) * 8;

  f32x4 acc[4][4] = {};

  // staging geometry: chunk c = i*256 + tid covers LDS bytes [c*16, c*16+16)
  // row = c>>3 (64 cols * 2B = 128B = 8 chunks/row), colstart = (c&7)*8 elems
  int rbase = tid >> 3;         // 0..31
  int colb  = (tid & 7) * 8;
  const __bf16* Ab = A + (m0 + rbase) * K + colb;
  const __bf16* Bb = BT + ((long)n0 + rbase) * K + colb;
  __bf16* sAp = sA + tid * 8;
  __bf16* sBp = sB + tid * 8;

  for (int k0 = 0; k0 < K; k0 += 64) {
#pragma unroll
    for (int i = 0; i < 4; ++i) {
      gl_lds16(Ab + (long)i * 32 * K + k0, sAp + i * 2048);
      gl_lds16(Bb + (long)i * 32 * K + k0, sBp + i * 2048);
    }
    asm volatile("s_waitcnt vmcnt(0)" ::: "memory");
    __syncthreads();

#pragma unroll
    for (int kk = 0; kk < 2; ++kk) {
      int ko = kk * 32 + lko;
      bf16x8 af[4], bfr[4];
#pragma unroll
      for (int mi = 0; mi < 4; ++mi)
        af[mi] = *(const bf16x8*)(sA + (wr * 64 + mi * 16 + lrow) * 64 + ko);
#pragma unroll
      for (int ni = 0; ni < 4; ++ni)
        bfr[ni] = *(const bf16x8*)(sB + (wc * 64 + ni * 16 + lrow) * 64 + ko);
#pragma unroll
      for (int mi = 0; mi < 4; ++mi)
#pragma unroll
        for (int ni = 0; ni < 4; ++ni)
          acc[mi][ni] = __builtin_amdgcn_mfma_f32_16x16x32_bf16(
              af[mi], bfr[ni], acc[mi][ni], 0, 0, 0);
    }
    __syncthreads();
  }

  // epilogue: bias + relu + bf16 store.  C/D layout: col = lane&15,
  // row = (lane>>4)*4 + r   [verified m89/m91]
#pragma unroll
  for (int ni = 0; ni < 4; ++ni) {
    int col = n0 + wc * 64 + ni * 16 + lrow;
    float bv = bias[col];
#pragma unroll
    for (int mi = 0; mi < 4; ++mi) {
      long row = m0 + wr * 64 + mi * 16 + (lane >> 4) * 4;
#pragma unroll
      for (int r = 0; r < 4; ++r) {
        float v = acc[mi][ni][r] + bv;
        v = v > 0.f ? v : 0.f;
        C[(row + r) * N + col] = (__bf16)v;
      }
    }
  }
}

// ---------------------------------------------------------------------------
// Tower: per 16-row wave, compute all 4 domains (256->128->64->1), select own.
// A-fragments (h2 rows) and B-fragments (tower weights, L2-resident) read
// straight from global.  t1/t2 K-redistribution through per-wave LDS.
// ---------------------------------------------------------------------------
__global__ __launch_bounds__(256) void k_tower(const __bf16* __restrict__ h2,
                                               const __bf16* __restrict__ TW1T,
                                               const __bf16* __restrict__ TW2T,
                                               const float* __restrict__ Tb1,
                                               const float* __restrict__ Tb2,
                                               const float* __restrict__ TW3,
                                               const float* __restrict__ Tb3,
                                               const int* __restrict__ dom,
                                               float* __restrict__ out) {
  __shared__ __bf16 t_lds[4][16 * 128];   // per-wave scratch (t1 then t2)
  int tid  = threadIdx.x;
  int lane = tid & 63;
  int w    = tid >> 6;
  int row  = lane & 15;        // fragment row / output col within 16
  int kq   = lane >> 4;        // k-quarter
  int m0r  = blockIdx.x * 64 + w * 16 + row;   // this lane's global row
  int mydom = dom[m0r];

  // Hoist h2 fragments (K=256 -> 8 k-slices of 32)
  bf16x8 a1[8];
#pragma unroll
  for (int kk = 0; kk < 8; ++kk)
    a1[kk] = *(const bf16x8*)(h2 + (long)m0r * D2 + kk * 32 + kq * 8);

  for (int d = 0; d < NDOM; ++d) {
    // ---- t1 = relu(h2 @ TW1[d] + Tb1[d])  (16 x 128) ----
    f32x4 acc1[8] = {};
#pragma unroll
    for (int kk = 0; kk < 8; ++kk) {
#pragma unroll
      for (int ni = 0; ni < 8; ++ni) {
        bf16x8 b = *(const bf16x8*)(TW1T + ((long)(d * T1D + ni * 16 + row)) * D2 +
                                    kk * 32 + kq * 8);
        acc1[ni] = __builtin_amdgcn_mfma_f32_16x16x32_bf16(a1[kk], b, acc1[ni], 0, 0, 0);
      }
    }
#pragma unroll
    for (int ni = 0; ni < 8; ++ni) {
      float bv = Tb1[d * T1D + ni * 16 + row];
#pragma unroll
      for (int r = 0; r < 4; ++r) {
        float v = acc1[ni][r] + bv;
        v = v > 0.f ? v : 0.f;
        t_lds[w][(kq * 4 + r) * 128 + ni * 16 + row] = (__bf16)v;
      }
    }
    asm volatile("s_waitcnt lgkmcnt(0)" ::: "memory");

    // ---- t2 = relu(t1 @ TW2[d] + Tb2[d])  (16 x 64) ----
    bf16x8 a2[4];
#pragma unroll
    for (int kk = 0; kk < 4; ++kk)
      a2[kk] = *(const bf16x8*)(&t_lds[w][row * 128 + kk * 32 + kq * 8]);
    f32x4 acc2[4] = {};
#pragma unroll
    for (int kk = 0; kk < 4; ++kk) {
#pragma unroll
      for (int ni = 0; ni < 4; ++ni) {
        bf16x8 b = *(const bf16x8*)(TW2T + ((long)(d * T2D + ni * 16 + row)) * T1D +
                                    kk * 32 + kq * 8);
        acc2[ni] = __builtin_amdgcn_mfma_f32_16x16x32_bf16(a2[kk], b, acc2[ni], 0, 0, 0);
      }
    }
    asm volatile("s_waitcnt lgkmcnt(0)" ::: "memory");
#pragma unroll
    for (int ni = 0; ni < 4; ++ni) {
      float bv = Tb2[d * T2D + ni * 16 + row];
#pragma unroll
      for (int r = 0; r < 4; ++r) {
        float v = acc2[ni][r] + bv;
        v = v > 0.f ? v : 0.f;
        t_lds[w][(kq * 4 + r) * 64 + ni * 16 + row] = (__bf16)v;
      }
    }
    asm volatile("s_waitcnt lgkmcnt(0)" ::: "memory");

    // ---- logit + sigmoid + predicated store ----
    float s = 0.f;
#pragma unroll
    for (int j = 0; j < 16; ++j)
      s += (float)t_lds[w][row * 64 + kq * 16 + j] * TW3[d * T2D + kq * 16 + j];
    s += __shfl_xor(s, 16);
    s += __shfl_xor(s, 32);
    s += Tb3[d];
    if (kq == 0 && mydom == d)
      out[m0r] = 1.0f / (1.0f + expf(-s));
    __syncthreads();   // keep waves together before t_lds reuse next domain
  }
}

// ---------------------------------------------------------------------------
extern "C" void kernel_launch(void* const* d_in, const int* in_sizes, int n_in,
                              void* d_out, int out_size, void* d_ws, size_t ws_size,
                              hipStream_t stream) {
  const int*   fids = (const int*)d_in[0];
  const int*   dom  = (const int*)d_in[1];
  const float* emb  = (const float*)d_in[2];
  const float* W1   = (const float*)d_in[3];
  const float* b1   = (const float*)d_in[4];
  const float* W2   = (const float*)d_in[5];
  const float* b2   = (const float*)d_in[6];
  const float* TW1  = (const float*)d_in[7];
  const float* Tb1  = (const float*)d_in[8];
  const float* TW2  = (const float*)d_in[9];
  const float* Tb2  = (const float*)d_in[10];
  const float* TW3  = (const float*)d_in[11];
  const float* Tb3  = (const float*)d_in[12];
  float* out = (float*)d_out;

  char* ws = (char*)d_ws;
  __bf16* h    = (__bf16*)(ws);                      // 16384*640*2  = 20971520
  __bf16* W1T  = (__bf16*)(ws + 20971520);           // 512*640*2    = 655360
  __bf16* h1   = (__bf16*)(ws + 21626880);           // 16384*512*2  = 16777216
  __bf16* W2T  = (__bf16*)(ws + 38404096);           // 256*512*2    = 262144
  __bf16* h2   = (__bf16*)(ws + 38666240);           // 16384*256*2  = 8388608
  __bf16* TW1T = (__bf16*)(ws + 47054848);           // 4*128*256*2  = 262144
  __bf16* TW2T = (__bf16*)(ws + 47316992);           // 4*64*128*2   = 65536
  // total: 47382528 bytes

  // weight prep (transpose + bf16)
  k_transpose<<<dim3(512, 1), 256, 0, stream>>>(W1, W1T, DBOT, D1);
  k_transpose<<<dim3(128, 1), 256, 0, stream>>>(W2, W2T, D1, D2);
  k_transpose<<<dim3(32, NDOM), 256, 0, stream>>>(TW1, TW1T, D2, T1D);
  k_transpose<<<dim3(8, NDOM), 256, 0, stream>>>(TW2, TW2T, T1D, T2D);

  // embedding gather
  k_gather<<<B_SZ * F_SZ * 4 / 256, 256, 0, stream>>>(fids, emb, h);

  // bottom MLP
  k_gemm<<<(B_SZ / 128) * (D1 / 128), 256, 0, stream>>>(h, W1T, b1, h1,
                                                        B_SZ, D1, DBOT, D1 / 128);
  k_gemm<<<(B_SZ / 128) * (D2 / 128), 256, 0, stream>>>(h1, W2T, b2, h2,
                                                        B_SZ, D2, D1, D2 / 128);

  // towers + select + sigmoid
  k_tower<<<B_SZ / 64, 256, 0, stream>>>(h2, TW1T, TW2T, Tb1, Tb2, TW3, Tb3,
                                         dom, out);
}

// Round 2
// 112.136 us; speedup vs baseline: 1.0201x; 1.0201x over previous
//
#include <hip/hip_runtime.h>

// Problem constants
#define B_SZ  16384
#define F_SZ  20
#define V_SZ  100000
#define E_SZ  32
#define DBOT  640     // F*E
#define D1    512
#define D2    256
#define T1D   128
#define T2D   64
#define NDOM  4

typedef __bf16 bf16x8 __attribute__((ext_vector_type(8)));
typedef float  f32x4  __attribute__((ext_vector_type(4)));

#define GAS __attribute__((address_space(1)))
#define LAS __attribute__((address_space(3)))

__device__ __forceinline__ void gl_lds16(const void* g, void* l) {
  __builtin_amdgcn_global_load_lds((const GAS void*)g, (LAS void*)l, 16, 0, 0);
}

// ---------------------------------------------------------------------------
// One-shot weight prep: tiled (32x32, padded LDS) transpose + fp32->bf16 for
// W1, W2, TW1[d], TW2[d].  Coalesced reads AND writes, conflict-free LDS.
// Block ranges: [0,320) W1 | [320,448) W2 | [448,576) TW1 | [576,608) TW2
// ---------------------------------------------------------------------------
__global__ __launch_bounds__(256) void k_prep(const float* __restrict__ W1,
                                              const float* __restrict__ W2,
                                              const float* __restrict__ TW1,
                                              const float* __restrict__ TW2,
                                              __bf16* __restrict__ W1T,
                                              __bf16* __restrict__ W2T,
                                              __bf16* __restrict__ TW1T,
                                              __bf16* __restrict__ TW2T) {
  __shared__ float tile[32][33];
  int bid = blockIdx.x;
  const float* src; __bf16* dst; int K, N, tk, tn;
  if (bid < 320)      { src = W1;  dst = W1T;  K = DBOT; N = D1;  tk = bid >> 4; tn = bid & 15; }
  else if (bid < 448) { int t = bid - 320; src = W2; dst = W2T; K = D1; N = D2; tk = t >> 3; tn = t & 7; }
  else if (bid < 576) { int t = bid - 448; int d = t >> 5; t &= 31;
                        src = TW1 + (long)d * D2 * T1D; dst = TW1T + (long)d * D2 * T1D;
                        K = D2; N = T1D; tk = t >> 2; tn = t & 3; }
  else                { int t = bid - 576; int d = t >> 3; t &= 7;
                        src = TW2 + (long)d * T1D * T2D; dst = TW2T + (long)d * T1D * T2D;
                        K = T1D; N = T2D; tk = t >> 1; tn = t & 1; }
  int r = threadIdx.x >> 5, c = threadIdx.x & 31;
  int k0 = tk * 32, n0 = tn * 32;
#pragma unroll
  for (int i = 0; i < 4; ++i)
    tile[r + i * 8][c] = src[(long)(k0 + r + i * 8) * N + n0 + c];
  __syncthreads();
#pragma unroll
  for (int i = 0; i < 4; ++i)
    dst[(long)(n0 + r + i * 8) * K + k0 + c] = (__bf16)tile[c][r + i * 8];
}

// ---------------------------------------------------------------------------
// Embedding gather + convert: h[b][f*32+e] = bf16(emb[f][ids[b][f]][e])
// One thread handles 8 consecutive elements (32B in, 16B out).
// Block 0 also zeroes the domain counters for the partition pass (next launch).
// ---------------------------------------------------------------------------
__global__ __launch_bounds__(256) void k_gather(const int* __restrict__ fids,
                                                const float* __restrict__ emb,
                                                __bf16* __restrict__ h,
                                                int* __restrict__ cnt) {
  if (blockIdx.x == 0 && threadIdx.x < NDOM) cnt[threadIdx.x] = 0;
  int t = blockIdx.x * 256 + threadIdx.x;   // 0 .. B*F*4
  int chunk = t & 3;
  int bf = t >> 2;
  int b = bf / F_SZ;
  int f = bf - b * F_SZ;
  int id = fids[bf];
  const float* src = emb + ((long)f * V_SZ + id) * E_SZ + chunk * 8;
  float4 v0 = *(const float4*)src;
  float4 v1 = *(const float4*)(src + 4);
  bf16x8 o;
  o[0] = (__bf16)v0.x; o[1] = (__bf16)v0.y; o[2] = (__bf16)v0.z; o[3] = (__bf16)v0.w;
  o[4] = (__bf16)v1.x; o[5] = (__bf16)v1.y; o[6] = (__bf16)v1.z; o[7] = (__bf16)v1.w;
  *(bf16x8*)(h + (long)b * DBOT + f * E_SZ + chunk * 8) = o;
}

// ---------------------------------------------------------------------------
// Partition rows by domain: per-domain index lists.  Ballot-aggregated so only
// one atomicAdd per wave per domain (1024 total, not 16384).
// Output order within a list is non-deterministic but per-row results are
// order-independent, so d_out stays deterministic.
// ---------------------------------------------------------------------------
__global__ __launch_bounds__(256) void k_partition(const int* __restrict__ dom,
                                                   int* __restrict__ cnt,
                                                   int* __restrict__ lists) {
  int i = blockIdx.x * 256 + threadIdx.x;
  int d = dom[i];
  int lane = threadIdx.x & 63;
#pragma unroll
  for (int dd = 0; dd < NDOM; ++dd) {
    unsigned long long md = __ballot(d == dd);
    if (d == dd) {
      int myoff = __popcll(md & ((1ull << lane) - 1ull));
      int leader = __ffsll((long long)md) - 1;
      int base = 0;
      if (lane == leader) base = atomicAdd(&cnt[dd], __popcll(md));
      base = __shfl(base, leader);
      lists[dd * B_SZ + base + myoff] = i;
    }
  }
}

// ---------------------------------------------------------------------------
// bf16 MFMA GEMM:  C[M][N] = relu(A[M][K] @ B[K][N] + bias),  B given as BT[N][K]
// 128x128 tile, BK=64, 256 threads = 4 waves in 2x2.  m97-style structure.
// ---------------------------------------------------------------------------
__global__ __launch_bounds__(256) void k_gemm(const __bf16* __restrict__ A,
                                              const __bf16* __restrict__ BT,
                                              const float* __restrict__ bias,
                                              __bf16* __restrict__ C,
                                              int M, int N, int K, int ntn) {
  __shared__ __bf16 sA[128 * 64];
  __shared__ __bf16 sB[128 * 64];
  int bid = blockIdx.x;
  int mt = bid / ntn, nt = bid - mt * ntn;
  long m0 = (long)mt * 128;
  int n0 = nt * 128;
  int tid  = threadIdx.x;
  int lane = tid & 63;
  int w    = tid >> 6;
  int wr = w >> 1, wc = w & 1;
  int lrow = lane & 15;
  int lko  = (lane >> 4) * 8;

  f32x4 acc[4][4] = {};

  int rbase = tid >> 3;         // 0..31
  int colb  = (tid & 7) * 8;
  const __bf16* Ab = A + (m0 + rbase) * K + colb;
  const __bf16* Bb = BT + ((long)n0 + rbase) * K + colb;
  __bf16* sAp = sA + tid * 8;
  __bf16* sBp = sB + tid * 8;

  for (int k0 = 0; k0 < K; k0 += 64) {
#pragma unroll
    for (int i = 0; i < 4; ++i) {
      gl_lds16(Ab + (long)i * 32 * K + k0, sAp + i * 2048);
      gl_lds16(Bb + (long)i * 32 * K + k0, sBp + i * 2048);
    }
    asm volatile("s_waitcnt vmcnt(0)" ::: "memory");
    __syncthreads();

#pragma unroll
    for (int kk = 0; kk < 2; ++kk) {
      int ko = kk * 32 + lko;
      bf16x8 af[4], bfr[4];
#pragma unroll
      for (int mi = 0; mi < 4; ++mi)
        af[mi] = *(const bf16x8*)(sA + (wr * 64 + mi * 16 + lrow) * 64 + ko);
#pragma unroll
      for (int ni = 0; ni < 4; ++ni)
        bfr[ni] = *(const bf16x8*)(sB + (wc * 64 + ni * 16 + lrow) * 64 + ko);
#pragma unroll
      for (int mi = 0; mi < 4; ++mi)
#pragma unroll
        for (int ni = 0; ni < 4; ++ni)
          acc[mi][ni] = __builtin_amdgcn_mfma_f32_16x16x32_bf16(
              af[mi], bfr[ni], acc[mi][ni], 0, 0, 0);
    }
    __syncthreads();
  }

  // epilogue: bias + relu + bf16 store.  C/D layout: col = lane&15,
  // row = (lane>>4)*4 + r   [verified m89/m91]
#pragma unroll
  for (int ni = 0; ni < 4; ++ni) {
    int col = n0 + wc * 64 + ni * 16 + lrow;
    float bv = bias[col];
#pragma unroll
    for (int mi = 0; mi < 4; ++mi) {
      long row = m0 + wr * 64 + mi * 16 + (lane >> 4) * 4;
#pragma unroll
      for (int r = 0; r < 4; ++r) {
        float v = acc[mi][ni][r] + bv;
        v = v > 0.f ? v : 0.f;
        C[(row + r) * N + col] = (__bf16)v;
      }
    }
  }
}

// ---------------------------------------------------------------------------
// Tower (domain-partitioned): block (x,y=d) handles 64 rows from lists[d].
// Each 16-row wave: 256->128->64->1 for its single domain, sigmoid, store.
// ---------------------------------------------------------------------------
__global__ __launch_bounds__(256) void k_tower(const __bf16* __restrict__ h2,
                                               const __bf16* __restrict__ TW1T,
                                               const __bf16* __restrict__ TW2T,
                                               const float* __restrict__ Tb1,
                                               const float* __restrict__ Tb2,
                                               const float* __restrict__ TW3,
                                               const float* __restrict__ Tb3,
                                               const int* __restrict__ cnt,
                                               const int* __restrict__ lists,
                                               float* __restrict__ out) {
  __shared__ __bf16 t_lds[4][16 * 128];   // per-wave scratch (t1 then t2)
  int d  = blockIdx.y;
  int nc = cnt[d];
  int base = blockIdx.x * 64;
  if (base >= nc) return;

  int tid  = threadIdx.x;
  int lane = tid & 63;
  int w    = tid >> 6;
  int row  = lane & 15;        // fragment row / output col within 16
  int kq   = lane >> 4;        // k-quarter
  int slot = base + w * 16 + row;
  bool valid = slot < nc;
  int m0r = lists[d * B_SZ + (valid ? slot : 0)];

  // Hoist h2 fragments (K=256 -> 8 k-slices of 32)
  bf16x8 a1[8];
#pragma unroll
  for (int kk = 0; kk < 8; ++kk)
    a1[kk] = *(const bf16x8*)(h2 + (long)m0r * D2 + kk * 32 + kq * 8);

  // ---- t1 = relu(h2 @ TW1[d] + Tb1[d])  (16 x 128) ----
  f32x4 acc1[8] = {};
#pragma unroll
  for (int kk = 0; kk < 8; ++kk) {
#pragma unroll
    for (int ni = 0; ni < 8; ++ni) {
      bf16x8 b = *(const bf16x8*)(TW1T + ((long)(d * T1D + ni * 16 + row)) * D2 +
                                  kk * 32 + kq * 8);
      acc1[ni] = __builtin_amdgcn_mfma_f32_16x16x32_bf16(a1[kk], b, acc1[ni], 0, 0, 0);
    }
  }
#pragma unroll
  for (int ni = 0; ni < 8; ++ni) {
    float bv = Tb1[d * T1D + ni * 16 + row];
#pragma unroll
    for (int r = 0; r < 4; ++r) {
      float v = acc1[ni][r] + bv;
      v = v > 0.f ? v : 0.f;
      t_lds[w][(kq * 4 + r) * 128 + ni * 16 + row] = (__bf16)v;
    }
  }
  asm volatile("s_waitcnt lgkmcnt(0)" ::: "memory");

  // ---- t2 = relu(t1 @ TW2[d] + Tb2[d])  (16 x 64) ----
  bf16x8 a2[4];
#pragma unroll
  for (int kk = 0; kk < 4; ++kk)
    a2[kk] = *(const bf16x8*)(&t_lds[w][row * 128 + kk * 32 + kq * 8]);
  f32x4 acc2[4] = {};
#pragma unroll
  for (int kk = 0; kk < 4; ++kk) {
#pragma unroll
    for (int ni = 0; ni < 4; ++ni) {
      bf16x8 b = *(const bf16x8*)(TW2T + ((long)(d * T2D + ni * 16 + row)) * T1D +
                                  kk * 32 + kq * 8);
      acc2[ni] = __builtin_amdgcn_mfma_f32_16x16x32_bf16(a2[kk], b, acc2[ni], 0, 0, 0);
    }
  }
  asm volatile("s_waitcnt lgkmcnt(0)" ::: "memory");
#pragma unroll
  for (int ni = 0; ni < 4; ++ni) {
    float bv = Tb2[d * T2D + ni * 16 + row];
#pragma unroll
    for (int r = 0; r < 4; ++r) {
      float v = acc2[ni][r] + bv;
      v = v > 0.f ? v : 0.f;
      t_lds[w][(kq * 4 + r) * 64 + ni * 16 + row] = (__bf16)v;
    }
  }
  asm volatile("s_waitcnt lgkmcnt(0)" ::: "memory");

  // ---- logit + sigmoid + predicated store ----
  float s = 0.f;
#pragma unroll
  for (int j = 0; j < 16; ++j)
    s += (float)t_lds[w][row * 64 + kq * 16 + j] * TW3[d * T2D + kq * 16 + j];
  s += __shfl_xor(s, 16);
  s += __shfl_xor(s, 32);
  s += Tb3[d];
  if (valid && kq == 0)
    out[m0r] = 1.0f / (1.0f + expf(-s));
}

// ---------------------------------------------------------------------------
extern "C" void kernel_launch(void* const* d_in, const int* in_sizes, int n_in,
                              void* d_out, int out_size, void* d_ws, size_t ws_size,
                              hipStream_t stream) {
  const int*   fids = (const int*)d_in[0];
  const int*   dom  = (const int*)d_in[1];
  const float* emb  = (const float*)d_in[2];
  const float* W1   = (const float*)d_in[3];
  const float* b1   = (const float*)d_in[4];
  const float* W2   = (const float*)d_in[5];
  const float* b2   = (const float*)d_in[6];
  const float* TW1  = (const float*)d_in[7];
  const float* Tb1  = (const float*)d_in[8];
  const float* TW2  = (const float*)d_in[9];
  const float* Tb2  = (const float*)d_in[10];
  const float* TW3  = (const float*)d_in[11];
  const float* Tb3  = (const float*)d_in[12];
  float* out = (float*)d_out;

  char* ws = (char*)d_ws;
  __bf16* h     = (__bf16*)(ws);                      // 16384*640*2  = 20971520
  __bf16* W1T   = (__bf16*)(ws + 20971520);           // 512*640*2    = 655360
  __bf16* h1    = (__bf16*)(ws + 21626880);           // 16384*512*2  = 16777216
  __bf16* W2T   = (__bf16*)(ws + 38404096);           // 256*512*2    = 262144
  __bf16* h2    = (__bf16*)(ws + 38666240);           // 16384*256*2  = 8388608
  __bf16* TW1T  = (__bf16*)(ws + 47054848);           // 4*128*256*2  = 262144
  __bf16* TW2T  = (__bf16*)(ws + 47316992);           // 4*64*128*2   = 65536
  int*    lists = (int*)(ws + 47382528);              // 4*16384*4    = 262144
  int*    cnt   = (int*)(ws + 47644672);              // 4*4 (pad 256)
  // total: ~47.6 MB

  // weight prep (tiled transpose + bf16), all four weights in one launch
  k_prep<<<608, 256, 0, stream>>>(W1, W2, TW1, TW2, W1T, W2T, TW1T, TW2T);

  // embedding gather (+ zero domain counters for the partition pass)
  k_gather<<<B_SZ * F_SZ * 4 / 256, 256, 0, stream>>>(fids, emb, h, cnt);

  // domain partition
  k_partition<<<B_SZ / 256, 256, 0, stream>>>(dom, cnt, lists);

  // bottom MLP
  k_gemm<<<(B_SZ / 128) * (D1 / 128), 256, 0, stream>>>(h, W1T, b1, h1,
                                                        B_SZ, D1, DBOT, D1 / 128);
  k_gemm<<<(B_SZ / 128) * (D2 / 128), 256, 0, stream>>>(h1, W2T, b2, h2,
                                                        B_SZ, D2, D1, D2 / 128);

  // towers + sigmoid + select (domain-partitioned, 1 domain per row)
  k_tower<<<dim3(B_SZ / 64, NDOM), 256, 0, stream>>>(h2, TW1T, TW2T, Tb1, Tb2,
                                                     TW3, Tb3, cnt, lists, out);
}

// Round 3
// 54.937 us; speedup vs baseline: 2.0821x; 2.0412x over previous
//
#include <hip/hip_runtime.h>

#define B_SZ  16384
#define F_SZ  20
#define V_SZ  100000
#define E_SZ  32
#define DBOT  640
#define D1    512
#define D2    256
#define T1D   128
#define T2D   64
#define NDOM  4

typedef __bf16 bf16x8 __attribute__((ext_vector_type(8)));
typedef float  f32x4  __attribute__((ext_vector_type(4)));

#define MFMA(a, b, c) __builtin_amdgcn_mfma_f32_16x16x32_bf16((a), (b), (c), 0, 0, 0)

// ---------------------------------------------------------------------------
// Prep: pack all weights into MFMA-fragment order bf16:
//   P[ntile][kstep][lane][8] holds BT[ntile*16 + (lane&15)][kstep*32 + (lane>>4)*8 + e]
// so a wave's B-fragment load is one coalesced 1KB global_load_dwordx4.
// Block ranges: [0,160) W1P | [160,224) W2P | [224,288) TW1P | [288,304) TW2P
// Block 304 zeroes the domain counters.
// ---------------------------------------------------------------------------
__global__ __launch_bounds__(256) void k_prep(const float* __restrict__ W1,
                                              const float* __restrict__ W2,
                                              const float* __restrict__ TW1,
                                              const float* __restrict__ TW2,
                                              __bf16* __restrict__ W1P,
                                              __bf16* __restrict__ W2P,
                                              __bf16* __restrict__ TW1P,
                                              __bf16* __restrict__ TW2P,
                                              int* __restrict__ cnt) {
  int bid = blockIdx.x, tid = threadIdx.x;
  const float* src; __bf16* dst; int n, k, N;
  if (bid < 160) {           // W1P: K=640 (20 ksteps), N=512 (32 ntiles)
    long g = (long)bid * 256 + tid;
    int lane = g & 63; int kkg = (int)((g >> 6) % 20); int ntile = (int)(g / 1280);
    n = ntile * 16 + (lane & 15); k = kkg * 32 + ((lane >> 4) << 3);
    src = W1; N = D1; dst = W1P + g * 8;
  } else if (bid < 224) {    // W2P: K=512 (16), N=256 (16)
    long g = (long)(bid - 160) * 256 + tid;
    int lane = g & 63; int kkg = (int)((g >> 6) & 15); int ntile = (int)(g >> 10);
    n = ntile * 16 + (lane & 15); k = kkg * 32 + ((lane >> 4) << 3);
    src = W2; N = D2; dst = W2P + g * 8;
  } else if (bid < 288) {    // TW1P: per-domain K=256 (8), N=128 (8)
    long g = (long)(bid - 224) * 256 + tid;
    int d = (int)(g >> 12); long r = g & 4095;
    int lane = r & 63; int kkg = (int)((r >> 6) & 7); int ntile = (int)(r >> 9);
    n = ntile * 16 + (lane & 15); k = kkg * 32 + ((lane >> 4) << 3);
    src = TW1 + (long)d * D2 * T1D; N = T1D;
    dst = TW1P + ((long)(d * 64 + ntile * 8 + kkg) * 64 + lane) * 8;
  } else if (bid < 304) {    // TW2P: per-domain K=128 (4), N=64 (4)
    long g = (long)(bid - 288) * 256 + tid;
    int d = (int)(g >> 10); long r = g & 1023;
    int lane = r & 63; int kkg = (int)((r >> 6) & 3); int ntile = (int)(r >> 8);
    n = ntile * 16 + (lane & 15); k = kkg * 32 + ((lane >> 4) << 3);
    src = TW2 + (long)d * T1D * T2D; N = T2D;
    dst = TW2P + ((long)(d * 16 + ntile * 4 + kkg) * 64 + lane) * 8;
  } else {
    if (tid < NDOM) cnt[tid] = 0;
    return;
  }
  bf16x8 o;
#pragma unroll
  for (int e = 0; e < 8; ++e) o[e] = (__bf16)src[(long)(k + e) * N + n];
  *(bf16x8*)dst = o;
}

// ---------------------------------------------------------------------------
// Fused: gather + GEMM1 (640->512, relu) + GEMM2 (512->256, relu) per
// 64-row panel.  512 threads = 8 waves (each 64x64 of h1, 64x32 of h2).
// A-tiles gathered from emb into XOR-swizzled LDS (dbuf, 1 barrier/step,
// T14 issue-early); B-frags from packed weights (coalesced, L2-resident);
// h1 lives only in LDS.  Blocks 0-63 also partition rows by domain.
// ---------------------------------------------------------------------------
__global__ __launch_bounds__(512) void k_fused(const int* __restrict__ fids,
                                               const int* __restrict__ dom,
                                               const float* __restrict__ emb,
                                               const __bf16* __restrict__ W1P,
                                               const float* __restrict__ b1,
                                               const __bf16* __restrict__ W2P,
                                               const float* __restrict__ b2,
                                               __bf16* __restrict__ h2,
                                               int* __restrict__ cnt,
                                               int* __restrict__ lists) {
  __shared__ int   ids_lds[64 * F_SZ];
  __shared__ __bf16 sA[2][64 * 64];
  __shared__ __bf16 h1[64 * D1];

  int bid = blockIdx.x, tid = threadIdx.x;
  int lane = tid & 63, w = tid >> 6;
  int lrow = lane & 15, kq = lane >> 4;
  int m0 = bid * 64;

  // ---- domain partition (blocks 0-63, waves 0-3) ----
  if (bid < 64 && tid < 256) {
    int i = bid * 256 + tid;
    int d = dom[i];
    int pl = tid & 63;
#pragma unroll
    for (int dd = 0; dd < NDOM; ++dd) {
      unsigned long long md = __ballot(d == dd);
      if (d == dd) {
        int myoff = __popcll(md & ((1ull << pl) - 1ull));
        int leader = __ffsll((long long)md) - 1;
        int base = 0;
        if (pl == leader) base = atomicAdd(&cnt[dd], __popcll(md));
        base = __shfl(base, leader);
        lists[dd * B_SZ + base + myoff] = i;
      }
    }
  }

  // ---- stage feature ids ----
  for (int i = tid; i < 64 * F_SZ; i += 512) ids_lds[i] = fids[m0 * F_SZ + i];
  __syncthreads();

  // staging geometry: thread -> (row, 16B chunk); chunk c covers feature
  // 2s+(c>>2), elems (c&3)*8.  LDS dest XOR-swizzled by row&7.
  int srow = tid >> 3, sc = tid & 7;
  int sbyte = srow * 128 + ((sc ^ (srow & 7)) << 4);

  float4 g0, g1;
  {
    int f = sc >> 2;
    int id = ids_lds[srow * F_SZ + f];
    const float* p = emb + ((long)f * V_SZ + id) * E_SZ + ((sc & 3) << 3);
    g0 = *(const float4*)p; g1 = *(const float4*)(p + 4);
  }

  f32x4 acc[4][4] = {};

  for (int s = 0; s < 10; ++s) {
    // commit staged regs -> LDS buf
    bf16x8 o;
    o[0] = (__bf16)g0.x; o[1] = (__bf16)g0.y; o[2] = (__bf16)g0.z; o[3] = (__bf16)g0.w;
    o[4] = (__bf16)g1.x; o[5] = (__bf16)g1.y; o[6] = (__bf16)g1.z; o[7] = (__bf16)g1.w;
    *(bf16x8*)((char*)&sA[s & 1][0] + sbyte) = o;
    // issue next step's gather early (T14): latency hides under MFMA below
    if (s < 9) {
      int f = 2 * (s + 1) + (sc >> 2);
      int id = ids_lds[srow * F_SZ + f];
      const float* p = emb + ((long)f * V_SZ + id) * E_SZ + ((sc & 3) << 3);
      g0 = *(const float4*)p; g1 = *(const float4*)(p + 4);
    }
    __syncthreads();   // single barrier/step: dbuf makes write(s+1) vs read(s) safe

    const char* sAb = (const char*)&sA[s & 1][0];
#pragma unroll
    for (int kk = 0; kk < 2; ++kk) {
      bf16x8 af[4];
#pragma unroll
      for (int mi = 0; mi < 4; ++mi) {
        int byte = ((mi * 16 + lrow) * 128 + (kk * 32 + kq * 8) * 2) ^ ((lrow & 7) << 4);
        af[mi] = *(const bf16x8*)(sAb + byte);
      }
#pragma unroll
      for (int ni = 0; ni < 4; ++ni) {
        bf16x8 bfr = *(const bf16x8*)(W1P +
            ((long)((w * 4 + ni) * 20 + (s * 2 + kk)) * 64 + lane) * 8);
#pragma unroll
        for (int mi = 0; mi < 4; ++mi)
          acc[mi][ni] = MFMA(af[mi], bfr, acc[mi][ni]);
      }
    }
  }

  // ---- h1 = relu(. + b1) -> LDS (XOR-swizzled rows, 1024B stride) ----
#pragma unroll
  for (int ni = 0; ni < 4; ++ni) {
    int col = w * 64 + ni * 16 + lrow;
    float bv = b1[col];
#pragma unroll
    for (int mi = 0; mi < 4; ++mi) {
#pragma unroll
      for (int r = 0; r < 4; ++r) {
        int row = mi * 16 + kq * 4 + r;
        float v = acc[mi][ni][r] + bv;
        v = v > 0.f ? v : 0.f;
        int byte = (row * 1024 + col * 2) ^ ((row & 7) << 4);
        *(__bf16*)((char*)h1 + byte) = (__bf16)v;
      }
    }
  }
  __syncthreads();

  // ---- GEMM2: h2 = relu(h1 @ W2 + b2), K=512 (16 ksteps) ----
  f32x4 acc2[4][2] = {};
  for (int kkg = 0; kkg < 16; ++kkg) {
    bf16x8 a2[4];
#pragma unroll
    for (int mi = 0; mi < 4; ++mi) {
      int byte = ((mi * 16 + lrow) * 1024 + kkg * 64 + kq * 16) ^ ((lrow & 7) << 4);
      a2[mi] = *(const bf16x8*)((const char*)h1 + byte);
    }
#pragma unroll
    for (int ni = 0; ni < 2; ++ni) {
      bf16x8 bfr = *(const bf16x8*)(W2P +
          ((long)((w * 2 + ni) * 16 + kkg) * 64 + lane) * 8);
#pragma unroll
      for (int mi = 0; mi < 4; ++mi)
        acc2[mi][ni] = MFMA(a2[mi], bfr, acc2[mi][ni]);
    }
  }

  // ---- h2 store (bf16, bias+relu) ----
#pragma unroll
  for (int ni = 0; ni < 2; ++ni) {
    int col = w * 32 + ni * 16 + lrow;
    float bv = b2[col];
#pragma unroll
    for (int mi = 0; mi < 4; ++mi) {
#pragma unroll
      for (int r = 0; r < 4; ++r) {
        long row = m0 + mi * 16 + kq * 4 + r;
        float v = acc2[mi][ni][r] + bv;
        v = v > 0.f ? v : 0.f;
        h2[row * D2 + col] = (__bf16)v;
      }
    }
  }
}

// ---------------------------------------------------------------------------
// Tower (domain-partitioned): block (x, y=d) -> 64 rows from lists[d].
// B-frags from packed TW1P/TW2P (coalesced 1KB/wave loads, L2-resident).
// ---------------------------------------------------------------------------
__global__ __launch_bounds__(256) void k_tower(const __bf16* __restrict__ h2,
                                               const __bf16* __restrict__ TW1P,
                                               const __bf16* __restrict__ TW2P,
                                               const float* __restrict__ Tb1,
                                               const float* __restrict__ Tb2,
                                               const float* __restrict__ TW3,
                                               const float* __restrict__ Tb3,
                                               const int* __restrict__ cnt,
                                               const int* __restrict__ lists,
                                               float* __restrict__ out) {
  __shared__ __bf16 t_lds[4][16 * 128];
  int d  = blockIdx.y;
  int nc = cnt[d];
  int base = blockIdx.x * 64;
  if (base >= nc) return;

  int tid  = threadIdx.x;
  int lane = tid & 63;
  int w    = tid >> 6;
  int row  = lane & 15;
  int kq   = lane >> 4;
  int slot = base + w * 16 + row;
  bool valid = slot < nc;
  int m0r = lists[d * B_SZ + (valid ? slot : 0)];

  bf16x8 a1[8];
#pragma unroll
  for (int kk = 0; kk < 8; ++kk)
    a1[kk] = *(const bf16x8*)(h2 + (long)m0r * D2 + kk * 32 + kq * 8);

  // t1 = relu(h2 @ TW1[d] + Tb1[d])
  f32x4 acc1[8] = {};
#pragma unroll
  for (int kk = 0; kk < 8; ++kk) {
#pragma unroll
    for (int ni = 0; ni < 8; ++ni) {
      bf16x8 b = *(const bf16x8*)(TW1P +
          ((long)(d * 64 + ni * 8 + kk) * 64 + lane) * 8);
      acc1[ni] = MFMA(a1[kk], b, acc1[ni]);
    }
  }
#pragma unroll
  for (int ni = 0; ni < 8; ++ni) {
    float bv = Tb1[d * T1D + ni * 16 + row];
#pragma unroll
    for (int r = 0; r < 4; ++r) {
      float v = acc1[ni][r] + bv;
      v = v > 0.f ? v : 0.f;
      t_lds[w][(kq * 4 + r) * 128 + ni * 16 + row] = (__bf16)v;
    }
  }
  asm volatile("s_waitcnt lgkmcnt(0)" ::: "memory");

  // t2 = relu(t1 @ TW2[d] + Tb2[d])
  bf16x8 a2[4];
#pragma unroll
  for (int kk = 0; kk < 4; ++kk)
    a2[kk] = *(const bf16x8*)(&t_lds[w][row * 128 + kk * 32 + kq * 8]);
  f32x4 acc2[4] = {};
#pragma unroll
  for (int kk = 0; kk < 4; ++kk) {
#pragma unroll
    for (int ni = 0; ni < 4; ++ni) {
      bf16x8 b = *(const bf16x8*)(TW2P +
          ((long)(d * 16 + ni * 4 + kk) * 64 + lane) * 8);
      acc2[ni] = MFMA(a2[kk], b, acc2[ni]);
    }
  }
  asm volatile("s_waitcnt lgkmcnt(0)" ::: "memory");
#pragma unroll
  for (int ni = 0; ni < 4; ++ni) {
    float bv = Tb2[d * T2D + ni * 16 + row];
#pragma unroll
    for (int r = 0; r < 4; ++r) {
      float v = acc2[ni][r] + bv;
      v = v > 0.f ? v : 0.f;
      t_lds[w][(kq * 4 + r) * 64 + ni * 16 + row] = (__bf16)v;
    }
  }
  asm volatile("s_waitcnt lgkmcnt(0)" ::: "memory");

  // logit + sigmoid + store
  float s = 0.f;
#pragma unroll
  for (int j = 0; j < 16; ++j)
    s += (float)t_lds[w][row * 64 + kq * 16 + j] * TW3[d * T2D + kq * 16 + j];
  s += __shfl_xor(s, 16);
  s += __shfl_xor(s, 32);
  s += Tb3[d];
  if (valid && kq == 0)
    out[m0r] = 1.0f / (1.0f + expf(-s));
}

// ---------------------------------------------------------------------------
extern "C" void kernel_launch(void* const* d_in, const int* in_sizes, int n_in,
                              void* d_out, int out_size, void* d_ws, size_t ws_size,
                              hipStream_t stream) {
  const int*   fids = (const int*)d_in[0];
  const int*   dom  = (const int*)d_in[1];
  const float* emb  = (const float*)d_in[2];
  const float* W1   = (const float*)d_in[3];
  const float* b1   = (const float*)d_in[4];
  const float* W2   = (const float*)d_in[5];
  const float* b2   = (const float*)d_in[6];
  const float* TW1  = (const float*)d_in[7];
  const float* Tb1  = (const float*)d_in[8];
  const float* TW2  = (const float*)d_in[9];
  const float* Tb2  = (const float*)d_in[10];
  const float* TW3  = (const float*)d_in[11];
  const float* Tb3  = (const float*)d_in[12];
  float* out = (float*)d_out;

  char* ws = (char*)d_ws;
  __bf16* W1P   = (__bf16*)(ws);                 // 655360
  __bf16* W2P   = (__bf16*)(ws + 655360);        // 262144
  __bf16* TW1P  = (__bf16*)(ws + 917504);        // 262144
  __bf16* TW2P  = (__bf16*)(ws + 1179648);       // 65536
  __bf16* h2    = (__bf16*)(ws + 1245184);       // 8388608
  int*    lists = (int*)(ws + 9633792);          // 262144
  int*    cnt   = (int*)(ws + 9895936);          // 16

  // 1) pack weights + zero counters
  k_prep<<<305, 256, 0, stream>>>(W1, W2, TW1, TW2, W1P, W2P, TW1P, TW2P, cnt);

  // 2) fused gather + GEMM1 + GEMM2 (+ partition in blocks 0-63)
  k_fused<<<256, 512, 0, stream>>>(fids, dom, emb, W1P, b1, W2P, b2, h2,
                                   cnt, lists);

  // 3) towers + sigmoid + select
  k_tower<<<dim3(80, NDOM), 256, 0, stream>>>(h2, TW1P, TW2P, Tb1, Tb2,
                                              TW3, Tb3, cnt, lists, out);
}